// Round 9
// baseline (479.595 us; speedup 1.0000x reference)
//
#include <hip/hip_runtime.h>
#include <math.h>

#define BB 4
#define QQ 75
#define CC 640
#define HW 100
#define NWAY 5
#define KSHOT 5
#define MS 500
#define MSP 512
#define MTOT 7500
#define MPAD 7680     // 30 tiles of 256
#define TEMPER 2.0f
#define EPSN 1e-8f
#define NCH 8         // n-chunks of 64 per way
#define LBS 32768     // one LDS slot: 256 rows x 32ch x 2B x {hi,lo}

typedef _Float16 v8h __attribute__((ext_vector_type(8)));
typedef float v4f __attribute__((ext_vector_type(4)));

__device__ inline void splitv(const float* x, v8h& hi, v8h& lo) {
#pragma unroll
    for (int j = 0; j < 8; ++j) {
        _Float16 h = (_Float16)x[j];
        float r0 = x[j] - (float)h;
        hi[j] = h; lo[j] = (_Float16)r0;
    }
}

typedef __attribute__((address_space(3))) unsigned int lds_uint;
typedef __attribute__((address_space(1))) const unsigned int glb_uint;
__device__ inline void gl_lds16(const void* g, void* l) {
    __builtin_amdgcn_global_load_lds((glb_uint*)g, (lds_uint*)l, 16, 0, 0);
}

// ---------------- norms: inverse channel-norms, query (300) + support (100) -----
// Query blocks: 5 channel-groups x 100 pixels (512 thr) -> 5x parallelism vs the
// old 1-thread-per-pixel serial-640 chain (latency-bound at 0.6 waves/SIMD).
// invq summation becomes chunked (5x128, fixed combine order) -- post-hoc scale;
// R5 measured chunked invq passing with absmax 0.0. Support blocks keep the
// serial c-order (bit-identical invs -> bit-identical B scaling).
// Also zeroes out[0] (accumulated by finalize's atomicAdd).
__global__ __launch_bounds__(512) void norms(const float* __restrict__ qx,
                                             const float* __restrict__ sup,
                                             float* __restrict__ invq,
                                             float* __restrict__ invs,
                                             float* __restrict__ out) {
    int bid = blockIdx.x, t = threadIdx.x;
    if (bid == 0 && t == 0) out[0] = 0.f;
    if (bid < BB * QQ) {
        __shared__ float part[5][HW];
        const float* src = qx + (size_t)bid * CC * HW;
        if (t < 500) {
            int g = t / HW, p = t % HW;
            float s = 0.f;
            for (int c = g * 128; c < (g + 1) * 128; ++c) {
                float v = src[c * HW + p]; s += v * v;
            }
            part[g][p] = s;
        }
        __syncthreads();
        if (t < HW) {
            float ss = ((((part[0][t] + part[1][t]) + part[2][t]) + part[3][t]) + part[4][t]);
            invq[bid * HW + t] = 1.f / (sqrtf(ss) + EPSN);
        }
    } else {
        int bs = bid - BB * QQ;
        const float* src = sup + (size_t)bs * CC * HW;
        if (t < HW) {
            float ss = 0.f;
            for (int c = 0; c < CC; ++c) { float v = src[c * HW + t]; ss += v * v; }
            invs[bs * HW + t] = 1.f / (sqrtf(ss) + EPSN);
        }
    }
}

// ---------------- prep_AB: transpose+split one 64-channel chunk per block --------
__global__ __launch_bounds__(256) void prep_AB(const float* __restrict__ qx,
                                               const float* __restrict__ sup,
                                               const float* __restrict__ invs,
                                               _Float16* __restrict__ Ahi,
                                               _Float16* __restrict__ Alo,
                                               _Float16* __restrict__ Bhi,
                                               _Float16* __restrict__ Blo) {
    int g = blockIdx.x;
    const float* src; const float* inv = 0;
    _Float16 *dh, *dl;
    int ct;
    if (g < BB * QQ * 10) {
        int bq = g / 10; ct = g % 10;
        int b = bq / QQ, qi = bq % QQ;
        src = qx + ((size_t)bq * CC + ct * 64) * HW;
        size_t rowbase = (size_t)b * MPAD + qi * HW;
        dh = Ahi + rowbase * CC; dl = Alo + rowbase * CC;
    } else {
        int h = g - BB * QQ * 10;
        int bs = h / 10; ct = h % 10;
        int b = bs / 25, s = bs % 25, w = s / KSHOT, shot = s % KSHOT;
        src = sup + ((size_t)bs * CC + ct * 64) * HW;
        size_t rowbase = (size_t)(b * NWAY + w) * MSP + shot * HW;
        dh = Bhi + rowbase * CC; dl = Blo + rowbase * CC;
        inv = invs + bs * HW;
    }
    __shared__ float tile[64 * 101];   // padded stride 101: transpose reads 2-way max
    __shared__ float invt[HW];
    int t = threadIdx.x;
    if (t < HW) invt[t] = inv ? inv[t] : 1.f;
    for (int i = t; i < 64 * HW; i += 256) tile[(i / HW) * 101 + (i % HW)] = src[i];
    __syncthreads();
    for (int cell = t; cell < 800; cell += 256) {
        int p = cell >> 3, oct = cell & 7;
        float iv = invt[p];
        float x[8];
#pragma unroll
        for (int j = 0; j < 8; ++j) x[j] = tile[(oct * 8 + j) * 101 + p] * iv;
        v8h hi, lo; splitv(x, hi, lo);
        size_t off = (size_t)p * CC + ct * 64 + oct * 8;
        *(v8h*)(dh + off) = hi;
        *(v8h*)(dl + off) = lo;
    }
}

// ---------------- simkernel: 256x256 tile, 4-phase/K-step (R6 = measured best) ---
// + XCD-AWARE BLOCK SWIZZLE (T1): physical block i -> XCD i%8 (round-robin), so
// logical bid = (i%8)*150 + i/8 puts 150 CONSECUTIVE logical tiles on one XCD.
// The 10 blocks sharing each 640KB A-slice (consecutive nt) now share one L2 ->
// expected FETCH 414MB -> ~130-180MB (A-slice fetched once per XCD, not 8x).
// 1200 % 8 == 0 -> bijective. Correctness-independent.
// Schedule (measured best of 7 variants, 297.5us/46%): phase order {ds_reads(p);
// DMA; barrier; lgkmcnt(0); MFMA(p)}; vmcnt(4) at P3 certifies A(ch+1)+B(ch+1)
// (FIFO [B(ch+1),A(ch+1),B(ch+2)]), leaving B(ch+2)x4 in flight (T4).
// Term-first MFMA interleave; per-acc term order (hi*bhi, hi*blo, lo*bhi; ch
// ascending) -> bitwise-identical pmax/pidx.
__global__ __launch_bounds__(512, 2) void simkernel(
        const _Float16* __restrict__ Ahi, const _Float16* __restrict__ Alo,
        const _Float16* __restrict__ Bhi, const _Float16* __restrict__ Blo,
        float* __restrict__ pmax, unsigned short* __restrict__ pidx) {
    __shared__ char lds_raw[5 * LBS];          // 163840 B

    int phys = blockIdx.x;
    int bid = (phys % 8) * 150 + phys / 8;     // XCD swizzle: 1200/8 = 150
    int nt = bid % 10; int t2 = bid / 10;
    int mt = t2 % 30;  int b = t2 / 30;
    int m0 = mt * 256;
    int w = nt >> 1, n0w = (nt & 1) * 256;

    int tid = threadIdx.x;
    int lane = tid & 63;
    int wvu = __builtin_amdgcn_readfirstlane(tid >> 6);

    // staging: 64 segs/K-step (A:32, B:32); each wave: 4 A segs + 4 B segs.
    int arrA = wvu >> 2;                       // 0: hi array, 1: lo array
    int rgbase = (wvu & 3) * 4;
    const char* Ab = (const char*)((arrA ? Alo : Ahi) + ((size_t)b * MPAD + m0) * CC);
    const char* Bb = (const char*)((arrA ? Blo : Bhi) + ((size_t)(b * NWAY + w) * MSP + n0w) * CC);

    int rr0 = lane >> 2;                               // row within 16-row segment
    int octsw = (lane & 3) ^ ((lane >> 3) & 3);        // XOR-swizzled octet (T2)
    int laneoff = rr0 * (CC * 2) + octsw * 16;

    const char* srcA[4]; const char* srcB[4]; int dof[4];
#pragma unroll
    for (int s = 0; s < 4; ++s) {
        int rg = rgbase + s;
        srcA[s] = Ab + (size_t)(rg * 16) * (CC * 2) + laneoff;
        srcB[s] = Bb + (size_t)(rg * 16) * (CC * 2) + laneoff;
        dof[s] = arrA * 16384 + rg * 1024;             // linear LDS dest (per slot)
    }
    char* ldsB = lds_raw + 2 * LBS;

    int wv = tid >> 6;
    int wm = wv >> 2, wn = wv & 3;                     // wave grid 2(M) x 4(N)
    int lq = lane >> 4, lc = lane & 15;

    int idxA[4], idxB[4];
#pragma unroll
    for (int mf = 0; mf < 4; ++mf) {
        int row = wm * 128 + mf * 16 + lc;
        idxA[mf] = row * 4 + (lq ^ ((row >> 1) & 3));  // +256 for mf+4 (swz invariant)
    }
#pragma unroll
    for (int nf = 0; nf < 4; ++nf) {
        int row = wn * 64 + nf * 16 + lc;
        idxB[nf] = row * 4 + (lq ^ ((row >> 1) & 3));
    }

    v4f acc[8][4];
#pragma unroll
    for (int mf = 0; mf < 8; ++mf)
#pragma unroll
        for (int nf = 0; nf < 4; ++nf) acc[mf][nf] = (v4f)0.f;

    // prologue: A(0)->Aslot0, B(0)->Bslot0, B(1)->Bslot1 (12 loads/wave in flight)
    // vmcnt(4) certifies A(0),B(0); leaves B(1)'s 4 in flight.
#pragma unroll
    for (int s = 0; s < 4; ++s) gl_lds16(srcA[s], lds_raw + dof[s]);
#pragma unroll
    for (int s = 0; s < 4; ++s) gl_lds16(srcB[s], ldsB + dof[s]);
#pragma unroll
    for (int s = 0; s < 4; ++s) gl_lds16(srcB[s] + 64, ldsB + LBS + dof[s]);
    asm volatile("s_waitcnt vmcnt(4)\n\ts_barrier" ::: "memory");

    for (int ch = 0; ch < 20; ++ch) {
        const char* cA = lds_raw + (ch & 1) * LBS;
        const char* cB = ldsB + (ch % 3) * LBS;
        const v8h* AHI = (const v8h*)cA;
        const v8h* ALO = (const v8h*)(cA + 16384);
        const v8h* BHI = (const v8h*)cB;
        const v8h* BLO = (const v8h*)(cB + 16384);
        char* nA = lds_raw + ((ch + 1) & 1) * LBS;
        char* nB = ldsB + ((ch + 2) % 3) * LBS;
        int offA = (ch + 1) * 64, offB = (ch + 2) * 64;

        v8h ahi[4], alo[4], a2hi[4], a2lo[4], bhi[4], blo[4];

        // ---- P0: reads A03(ch),B01(ch) [certified P3(ch-1)]; DMA A(ch+1)
#pragma unroll
        for (int m2 = 0; m2 < 4; ++m2) { ahi[m2] = AHI[idxA[m2]]; alo[m2] = ALO[idxA[m2]]; }
        bhi[0] = BHI[idxB[0]]; blo[0] = BLO[idxB[0]];
        bhi[1] = BHI[idxB[1]]; blo[1] = BLO[idxB[1]];
        if (ch < 19) {
#pragma unroll
            for (int s = 0; s < 4; ++s) gl_lds16(srcA[s] + offA, nA + dof[s]);
        }
        asm volatile("s_barrier\n\ts_waitcnt lgkmcnt(0)" ::: "memory");
        __builtin_amdgcn_s_setprio(1);
#pragma unroll
        for (int m2 = 0; m2 < 4; ++m2)
#pragma unroll
            for (int n2 = 0; n2 < 2; ++n2)
                acc[m2][n2] = __builtin_amdgcn_mfma_f32_16x16x32_f16(ahi[m2], bhi[n2], acc[m2][n2], 0, 0, 0);
#pragma unroll
        for (int m2 = 0; m2 < 4; ++m2)
#pragma unroll
            for (int n2 = 0; n2 < 2; ++n2)
                acc[m2][n2] = __builtin_amdgcn_mfma_f32_16x16x32_f16(ahi[m2], blo[n2], acc[m2][n2], 0, 0, 0);
#pragma unroll
        for (int m2 = 0; m2 < 4; ++m2)
#pragma unroll
            for (int n2 = 0; n2 < 2; ++n2)
                acc[m2][n2] = __builtin_amdgcn_mfma_f32_16x16x32_f16(alo[m2], bhi[n2], acc[m2][n2], 0, 0, 0);
        __builtin_amdgcn_s_setprio(0);

        // ---- P1: reads B23(ch); DMA B(ch+2) segs 0-1
        bhi[2] = BHI[idxB[2]]; blo[2] = BLO[idxB[2]];
        bhi[3] = BHI[idxB[3]]; blo[3] = BLO[idxB[3]];
        if (ch < 18) { gl_lds16(srcB[0] + offB, nB + dof[0]); gl_lds16(srcB[1] + offB, nB + dof[1]); }
        asm volatile("s_barrier\n\ts_waitcnt lgkmcnt(0)" ::: "memory");
        __builtin_amdgcn_s_setprio(1);
#pragma unroll
        for (int m2 = 0; m2 < 4; ++m2)
#pragma unroll
            for (int n2 = 2; n2 < 4; ++n2)
                acc[m2][n2] = __builtin_amdgcn_mfma_f32_16x16x32_f16(ahi[m2], bhi[n2], acc[m2][n2], 0, 0, 0);
#pragma unroll
        for (int m2 = 0; m2 < 4; ++m2)
#pragma unroll
            for (int n2 = 2; n2 < 4; ++n2)
                acc[m2][n2] = __builtin_amdgcn_mfma_f32_16x16x32_f16(ahi[m2], blo[n2], acc[m2][n2], 0, 0, 0);
#pragma unroll
        for (int m2 = 0; m2 < 4; ++m2)
#pragma unroll
            for (int n2 = 2; n2 < 4; ++n2)
                acc[m2][n2] = __builtin_amdgcn_mfma_f32_16x16x32_f16(alo[m2], bhi[n2], acc[m2][n2], 0, 0, 0);
        __builtin_amdgcn_s_setprio(0);

        // ---- P2: reads A47(ch); DMA B(ch+2) segs 2-3
#pragma unroll
        for (int m2 = 0; m2 < 4; ++m2) { a2hi[m2] = AHI[idxA[m2] + 256]; a2lo[m2] = ALO[idxA[m2] + 256]; }
        if (ch < 18) { gl_lds16(srcB[2] + offB, nB + dof[2]); gl_lds16(srcB[3] + offB, nB + dof[3]); }
        asm volatile("s_barrier\n\ts_waitcnt lgkmcnt(0)" ::: "memory");
        __builtin_amdgcn_s_setprio(1);
#pragma unroll
        for (int m2 = 0; m2 < 4; ++m2)
#pragma unroll
            for (int n2 = 0; n2 < 2; ++n2)
                acc[4 + m2][n2] = __builtin_amdgcn_mfma_f32_16x16x32_f16(a2hi[m2], bhi[n2], acc[4 + m2][n2], 0, 0, 0);
#pragma unroll
        for (int m2 = 0; m2 < 4; ++m2)
#pragma unroll
            for (int n2 = 0; n2 < 2; ++n2)
                acc[4 + m2][n2] = __builtin_amdgcn_mfma_f32_16x16x32_f16(a2hi[m2], blo[n2], acc[4 + m2][n2], 0, 0, 0);
#pragma unroll
        for (int m2 = 0; m2 < 4; ++m2)
#pragma unroll
            for (int n2 = 0; n2 < 2; ++n2)
                acc[4 + m2][n2] = __builtin_amdgcn_mfma_f32_16x16x32_f16(a2lo[m2], bhi[n2], acc[4 + m2][n2], 0, 0, 0);
        __builtin_amdgcn_s_setprio(0);

        // ---- P3: no reads; vmcnt(4) certifies A(ch+1)+B(ch+1), leaves B(ch+2)
        if (ch < 18) asm volatile("s_waitcnt vmcnt(4)\n\ts_barrier" ::: "memory");
        else         asm volatile("s_waitcnt vmcnt(0)\n\ts_barrier" ::: "memory");
        __builtin_amdgcn_s_setprio(1);
#pragma unroll
        for (int m2 = 0; m2 < 4; ++m2)
#pragma unroll
            for (int n2 = 2; n2 < 4; ++n2)
                acc[4 + m2][n2] = __builtin_amdgcn_mfma_f32_16x16x32_f16(a2hi[m2], bhi[n2], acc[4 + m2][n2], 0, 0, 0);
#pragma unroll
        for (int m2 = 0; m2 < 4; ++m2)
#pragma unroll
            for (int n2 = 2; n2 < 4; ++n2)
                acc[4 + m2][n2] = __builtin_amdgcn_mfma_f32_16x16x32_f16(a2hi[m2], blo[n2], acc[4 + m2][n2], 0, 0, 0);
#pragma unroll
        for (int m2 = 0; m2 < 4; ++m2)
#pragma unroll
            for (int n2 = 2; n2 < 4; ++n2)
                acc[4 + m2][n2] = __builtin_amdgcn_mfma_f32_16x16x32_f16(a2lo[m2], bhi[n2], acc[4 + m2][n2], 0, 0, 0);
        __builtin_amdgcn_s_setprio(0);
    }

    // ---- fused max/argmax epilogue (same tie rules as before: first-max wins) ----
    int chunk = (nt & 1) * 4 + wn;                     // 64-col chunk index of way
#pragma unroll
    for (int mf = 0; mf < 8; ++mf) {
#pragma unroll
        for (int r = 0; r < 4; ++r) {
            float v = -__builtin_inff(); int idx = 0x7fffffff;
#pragma unroll
            for (int nf = 0; nf < 4; ++nf) {
                int n_way = n0w + wn * 64 + nf * 16 + lc;
                float cv = acc[mf][nf][r];
                if (n_way < MS && cv > v) { v = cv; idx = n_way; }
            }
#pragma unroll
            for (int msk = 1; msk < 16; msk <<= 1) {
                float ov = __shfl_xor(v, msk);
                int oi = __shfl_xor(idx, msk);
                if (ov > v || (ov == v && oi < idx)) { v = ov; idx = oi; }
            }
            if (lc == 0) {
                int mrow = m0 + wm * 128 + mf * 16 + lq * 4 + r;
                size_t o = ((size_t)(b * NWAY + w) * NCH + chunk) * MPAD + mrow;
                pmax[o] = v;
                pidx[o] = (unsigned short)(idx & 0xffff);
            }
        }
    }
}

// ================= FALLBACK PATH (ws too small) =================
__global__ void norm_support(const float* __restrict__ sup, float* __restrict__ snre) {
    int bid = blockIdx.x;
    int b = bid / 25, s = bid % 25;
    int w = s / KSHOT, shot = s % KSHOT;
    const float* src = sup + (size_t)bid * CC * HW;
    float* dst = snre + ((size_t)(b * NWAY + w)) * CC * MSP + shot * HW;
    __shared__ float inv[HW];
    int t = threadIdx.x;
    if (t < HW) {
        float ss = 0.f;
        for (int c = 0; c < CC; ++c) { float v = src[c * HW + t]; ss += v * v; }
        inv[t] = 1.f / (sqrtf(ss) + EPSN);
    }
    __syncthreads();
    for (int i = t; i < CC * HW; i += 256) {
        int c = i / HW, p = i % HW;
        dst[c * MSP + p] = src[i] * inv[p];
    }
    if (shot == KSHOT - 1) {
        float* padbase = snre + ((size_t)(b * NWAY + w)) * CC * MSP;
        for (int i = t; i < CC * (MSP - MS); i += 256) {
            int c = i / (MSP - MS), j = i % (MSP - MS);
            padbase[c * MSP + MS + j] = 0.f;
        }
    }
}

__global__ __launch_bounds__(256) void simkernel_fb(
        const float* __restrict__ qx, const float* __restrict__ snre,
        float* __restrict__ pmax, unsigned short* __restrict__ pidx) {
    __shared__ char lds_fb[49152];
    v8h* AHI = (v8h*)(lds_fb);
    v8h* ALO = (v8h*)(lds_fb + 8192);
    v8h* BHI = (v8h*)(lds_fb + 16384);
    v8h* BLO = (v8h*)(lds_fb + 32768);

    int bid = blockIdx.x;
    int mt = bid % 60; int t2 = bid / 60;
    int nt = t2 % 10;  int b = t2 / 10;
    int m0 = mt * 128;
    int w = nt >> 1;
    int n0w = (nt & 1) * 256;

    int tid = threadIdx.x;
    const float* Abase = qx + (size_t)b * QQ * CC * HW;
    const float* Bbase = snre + (size_t)(b * NWAY + w) * CC * MSP;

    int oct = tid & 3;
    int arow = tid >> 2;
    int aqi[2], ap[2];
#pragma unroll
    for (int pass = 0; pass < 2; ++pass) {
        int mg = m0 + arow + pass * 64;
        if (mg >= MTOT) mg = 0;
        aqi[pass] = mg / HW; ap[pass] = mg % HW;
    }

    v4f acc[4][8];
#pragma unroll
    for (int mf = 0; mf < 4; ++mf)
#pragma unroll
        for (int nf = 0; nf < 8; ++nf) acc[mf][nf] = (v4f)0.f;

    int lane = tid & 63;
    int wv = tid >> 6;
    int mrow_w = (wv >> 1) * 64;
    int ncol_w = (wv & 1) * 128;
    int lq = lane >> 4, lc = lane & 15;

    for (int ch = 0; ch < 20; ++ch) {
        int c0 = ch * 32 + oct * 8;
        __syncthreads();
#pragma unroll
        for (int pass = 0; pass < 2; ++pass) {
            const float* src = Abase + ((size_t)aqi[pass] * CC + c0) * HW + ap[pass];
            float x[8];
#pragma unroll
            for (int j = 0; j < 8; ++j) x[j] = src[j * HW];
            v8h hi, lo; splitv(x, hi, lo);
            int cell = (arow + pass * 64) * 4 + oct;
            AHI[cell] = hi; ALO[cell] = lo;
        }
#pragma unroll
        for (int pass = 0; pass < 4; ++pass) {
            int nrow = arow + pass * 64;
            const float* src = Bbase + (size_t)c0 * MSP + n0w + nrow;
            float x[8];
#pragma unroll
            for (int j = 0; j < 8; ++j) x[j] = src[j * MSP];
            v8h hi, lo; splitv(x, hi, lo);
            int cell = nrow * 4 + oct;
            BHI[cell] = hi; BLO[cell] = lo;
        }
        __syncthreads();

        v8h ahi[4], alo[4];
#pragma unroll
        for (int mf = 0; mf < 4; ++mf) {
            int idx = (mrow_w + mf * 16 + lc) * 4 + lq;
            ahi[mf] = AHI[idx]; alo[mf] = ALO[idx];
        }
#pragma unroll
        for (int nf = 0; nf < 8; ++nf) {
            int idx = (ncol_w + nf * 16 + lc) * 4 + lq;
            v8h bhi = BHI[idx], blo = BLO[idx];
#pragma unroll
            for (int mf = 0; mf < 4; ++mf) {
                acc[mf][nf] = __builtin_amdgcn_mfma_f32_16x16x32_f16(ahi[mf], bhi, acc[mf][nf], 0, 0, 0);
                acc[mf][nf] = __builtin_amdgcn_mfma_f32_16x16x32_f16(ahi[mf], blo, acc[mf][nf], 0, 0, 0);
                acc[mf][nf] = __builtin_amdgcn_mfma_f32_16x16x32_f16(alo[mf], bhi, acc[mf][nf], 0, 0, 0);
            }
        }
    }

    int chunkidx = (nt & 1) * 2 + (wv & 1);   // 128-col chunk of the way
#pragma unroll
    for (int mf = 0; mf < 4; ++mf) {
#pragma unroll
        for (int r = 0; r < 4; ++r) {
            float v = -__builtin_inff(); int idx = 0x7fffffff;
#pragma unroll
            for (int nf = 0; nf < 8; ++nf) {
                int n_way = n0w + ncol_w + nf * 16 + lc;
                float cv = acc[mf][nf][r];
                if (n_way < MS && cv > v) { v = cv; idx = n_way; }
            }
#pragma unroll
            for (int msk = 1; msk < 16; msk <<= 1) {
                float ov = __shfl_xor(v, msk);
                int oi = __shfl_xor(idx, msk);
                if (ov > v || (ov == v && oi < idx)) { v = ov; idx = oi; }
            }
            if (lc == 0) {
                int mrow = m0 + mrow_w + mf * 16 + lq * 4 + r;
                size_t ob = (size_t)(b * NWAY + w) * NCH * MPAD + mrow;
                int s_hi = (idx != 0x7fffffff) ? (idx >> 6) : -1;  // 64-col slot
#pragma unroll
                for (int sl2 = 0; sl2 < 2; ++sl2) {
                    int sl = chunkidx * 2 + sl2;
                    if (sl == s_hi) {
                        pmax[ob + (size_t)sl * MPAD] = v;
                        pidx[ob + (size_t)sl * MPAD] = (unsigned short)(idx & 0xffff);
                    } else {
                        pmax[ob + (size_t)sl * MPAD] = -__builtin_inff();
                        pidx[ob + (size_t)sl * MPAD] = 0xffffu;
                    }
                }
            }
        }
    }
}

// ------- finalize: combine chunks + top-2 diff + mutual mask + predict + NLL -----
__global__ __launch_bounds__(128) void finalize(
        const float* __restrict__ pmax, const unsigned short* __restrict__ pidx,
        const float* __restrict__ invq, const int* __restrict__ qy,
        float* __restrict__ out) {
    int bq = blockIdx.x;
    int b = bq / QQ, qi = bq % QQ;
    __shared__ float sm[NWAY][HW];
    __shared__ int   si[NWAY][HW];
    __shared__ float diffv[HW];
    __shared__ int   nearest[HW];
    __shared__ float maskv[HW];
    __shared__ float pred[NWAY];
    int t = threadIdx.x;
    if (t < HW) {
        float iq = invq[bq * HW + t];
        for (int w = 0; w < NWAY; ++w) {
            size_t base = ((size_t)(b * NWAY + w) * NCH) * MPAD + qi * HW + t;
            float best = -__builtin_inff(); int bi = 0x7fffffff;
            for (int c = 0; c < NCH; ++c) {
                float v = pmax[base + (size_t)c * MPAD];
                if (v > best) { best = v; bi = pidx[base + (size_t)c * MPAD]; }
            }
            sm[w][t] = best * iq;
            si[w][t] = bi;
        }
    }
    __syncthreads();
    if (t < HW) {
        float v1 = -INFINITY, v2 = -INFINITY;
        float bestv = -INFINITY; int bestslot = 0;
        for (int w = 0; w < NWAY; ++w) {
            float v = sm[w][t];
            if (v > v1) { v2 = v1; v1 = v; } else if (v > v2) { v2 = v; }
            if (v > bestv) { bestv = v; bestslot = w * MS + si[w][t]; }
        }
        diffv[t] = v1 - v2;
        nearest[t] = bestslot;
    }
    __syncthreads();
    if (t < HW) {
        int slot = nearest[t];
        float bv = (nearest[0] == slot) ? diffv[0] : 0.f;
        int bm = 0;
        for (int m = 1; m < HW; ++m) {
            float val = (nearest[m] == slot) ? diffv[m] : 0.f;
            if (val > bv) { bv = val; bm = m; }
        }
        maskv[t] = (bm == t) ? TEMPER : 0.f;
    }
    __syncthreads();
    if (t < NWAY) {
        float s = 0.f;
        for (int m = 0; m < HW; ++m) s += sm[t][m] * maskv[m];
        pred[t] = s;
    }
    __syncthreads();
    if (t == 0) {
        float mx = pred[0];
        for (int w = 1; w < NWAY; ++w) mx = fmaxf(mx, pred[w]);
        float se = 0.f;
        for (int w = 0; w < NWAY; ++w) se += expf(pred[w] - mx);
        float lse = mx + logf(se);
        int y = qy[bq];
        atomicAdd(out, -(pred[y] - lse) * (1.f / (BB * QQ)));
    }
}

extern "C" void kernel_launch(void* const* d_in, const int* in_sizes, int n_in,
                              void* d_out, int out_size, void* d_ws, size_t ws_size,
                              hipStream_t stream) {
    const float* sup = (const float*)d_in[0];   // support_xf (4,25,640,10,10) f32
    const float* qx  = (const float*)d_in[2];   // query_xf   (4,75,640,10,10) f32
    const int*   qy  = (const int*)d_in[3];     // query_y    (4,75) int32
    float* out = (float*)d_out;

    // header region (~7.5 MB)
    size_t pcount = (size_t)BB * NWAY * NCH * MPAD;     // 1,228,800
    float* pmax = (float*)d_ws;
    unsigned short* pidx = (unsigned short*)(pmax + pcount);
    float* invq = (float*)(pidx + pcount);
    float* invs = invq + (size_t)BB * MTOT;             // actually BB*QQ*HW == BB*MTOT
    char*  big = (char*)(invs + (size_t)BB * 25 * HW);
    size_t header = (size_t)(big - (char*)d_ws);
    size_t needA = (size_t)BB * MPAD * CC * 2;          // 39.3 MB per array
    size_t needB = (size_t)BB * NWAY * MSP * CC * 2;    // 13.1 MB per array
    size_t need_fast = header + 2 * (needA + needB);

    hipLaunchKernelGGL(norms, dim3(BB * QQ + BB * 25), dim3(512), 0, stream,
                       qx, sup, invq, invs, out);

    if (ws_size >= need_fast) {
        _Float16* Ahi = (_Float16*)big;
        _Float16* Alo = Ahi + (size_t)BB * MPAD * CC;
        _Float16* Bhi = Alo + (size_t)BB * MPAD * CC;
        _Float16* Blo = Bhi + (size_t)BB * NWAY * MSP * CC;
        hipLaunchKernelGGL(prep_AB, dim3(BB * QQ * 10 + BB * 25 * 10), dim3(256), 0, stream,
                           qx, sup, invs, Ahi, Alo, Bhi, Blo);
        hipLaunchKernelGGL(simkernel, dim3(BB * 30 * 10), dim3(512), 0, stream,
                           Ahi, Alo, Bhi, Blo, pmax, pidx);
    } else {
        float* snre = (float*)big;   // 26.2 MB
        hipLaunchKernelGGL(norm_support, dim3(BB * 25), dim3(256), 0, stream, sup, snre);
        hipLaunchKernelGGL(simkernel_fb, dim3(BB * 10 * 60), dim3(256), 0, stream,
                           qx, snre, pmax, pidx);
    }
    hipLaunchKernelGGL(finalize, dim3(BB * QQ), dim3(128), 0, stream,
                       pmax, pidx, invq, qy, out);
}

// Round 10
// 461.970 us; speedup vs baseline: 1.0382x; 1.0382x over previous
//
#include <hip/hip_runtime.h>
#include <math.h>

#define BB 4
#define QQ 75
#define CC 640
#define HW 100
#define NWAY 5
#define KSHOT 5
#define MS 500
#define MSP 512
#define MTOT 7500
#define MPAD 7680     // 30 tiles of 256
#define TEMPER 2.0f
#define EPSN 1e-8f
#define NCH 8         // n-chunks of 64 per way
#define LBS 32768     // one LDS slot: 256 rows x 32ch x 2B x {hi,lo}

typedef _Float16 v8h __attribute__((ext_vector_type(8)));
typedef float v4f __attribute__((ext_vector_type(4)));

__device__ inline void splitv(const float* x, v8h& hi, v8h& lo) {
#pragma unroll
    for (int j = 0; j < 8; ++j) {
        _Float16 h = (_Float16)x[j];
        float r0 = x[j] - (float)h;
        hi[j] = h; lo[j] = (_Float16)r0;
    }
}

typedef __attribute__((address_space(3))) unsigned int lds_uint;
typedef __attribute__((address_space(1))) const unsigned int glb_uint;
__device__ inline void gl_lds16(const void* g, void* l) {
    __builtin_amdgcn_global_load_lds((glb_uint*)g, (lds_uint*)l, 16, 0, 0);
}

// ---------------- norms: inverse channel-norms, query (300) + support (100) -----
// R6-exact 128-thread version (every <=467us total used this; R9's 512-thread
// query-parallel variant cost ~20us of non-sim time -- reverted).
// Also zeroes out[0] (accumulated by finalize's atomicAdd).
__global__ __launch_bounds__(128) void norms(const float* __restrict__ qx,
                                             const float* __restrict__ sup,
                                             float* __restrict__ invq,
                                             float* __restrict__ invs,
                                             float* __restrict__ out) {
    int bid = blockIdx.x, t = threadIdx.x;
    if (bid == 0 && t == 0) out[0] = 0.f;
    const float* src; float* dst;
    if (bid < BB * QQ) { src = qx + (size_t)bid * CC * HW; dst = invq + bid * HW; }
    else { int bs = bid - BB * QQ; src = sup + (size_t)bs * CC * HW; dst = invs + bs * HW; }
    if (t < HW) {
        float ss = 0.f;
        for (int c = 0; c < CC; ++c) { float v = src[c * HW + t]; ss += v * v; }
        dst[t] = 1.f / (sqrtf(ss) + EPSN);
    }
}

// ---------------- prep_AB: transpose+split one 64-channel chunk per block --------
__global__ __launch_bounds__(256) void prep_AB(const float* __restrict__ qx,
                                               const float* __restrict__ sup,
                                               const float* __restrict__ invs,
                                               _Float16* __restrict__ Ahi,
                                               _Float16* __restrict__ Alo,
                                               _Float16* __restrict__ Bhi,
                                               _Float16* __restrict__ Blo) {
    int g = blockIdx.x;
    const float* src; const float* inv = 0;
    _Float16 *dh, *dl;
    int ct;
    if (g < BB * QQ * 10) {
        int bq = g / 10; ct = g % 10;
        int b = bq / QQ, qi = bq % QQ;
        src = qx + ((size_t)bq * CC + ct * 64) * HW;
        size_t rowbase = (size_t)b * MPAD + qi * HW;
        dh = Ahi + rowbase * CC; dl = Alo + rowbase * CC;
    } else {
        int h = g - BB * QQ * 10;
        int bs = h / 10; ct = h % 10;
        int b = bs / 25, s = bs % 25, w = s / KSHOT, shot = s % KSHOT;
        src = sup + ((size_t)bs * CC + ct * 64) * HW;
        size_t rowbase = (size_t)(b * NWAY + w) * MSP + shot * HW;
        dh = Bhi + rowbase * CC; dl = Blo + rowbase * CC;
        inv = invs + bs * HW;
    }
    __shared__ float tile[64 * 101];   // padded stride 101: transpose reads 2-way max
    __shared__ float invt[HW];
    int t = threadIdx.x;
    if (t < HW) invt[t] = inv ? inv[t] : 1.f;
    for (int i = t; i < 64 * HW; i += 256) tile[(i / HW) * 101 + (i % HW)] = src[i];
    __syncthreads();
    for (int cell = t; cell < 800; cell += 256) {
        int p = cell >> 3, oct = cell & 7;
        float iv = invt[p];
        float x[8];
#pragma unroll
        for (int j = 0; j < 8; ++j) x[j] = tile[(oct * 8 + j) * 101 + p] * iv;
        v8h hi, lo; splitv(x, hi, lo);
        size_t off = (size_t)p * CC + ct * 64 + oct * 8;
        *(v8h*)(dh + off) = hi;
        *(v8h*)(dl + off) = lo;
    }
}

// ---------------- simkernel: 256x256 tile, 4-phase/K-step (R6) + XCD swizzle -----
// Grid: physical block i -> XCD i%8; logical bid = (i%8)*150 + i/8 so the 10
// blocks sharing each 640KB A-slice land on one XCD's L2 (measured: FETCH
// 414MB -> 177MB, sim 297.5 -> 292.5us). 1200 % 8 == 0 -> bijective.
// Schedule (measured best of 7 structural variants): phase order {ds_reads(p);
// DMA; barrier; lgkmcnt(0); MFMA(p)}; vmcnt(4) at P3 certifies A(ch+1)+B(ch+1)
// (FIFO [B(ch+1),A(ch+1),B(ch+2)]), leaving B(ch+2)x4 in flight (T4).
// Term-first MFMA interleave; per-acc term order (hi*bhi, hi*blo, lo*bhi; ch
// ascending) -> bitwise-identical pmax/pidx.
// Counter state at this config: MfmaUtil 46.6% (busy-cycles == computed per-SIMD
// MFMA work), HBM 8%, bank-conflicts 0, WRITE 7200 (no spill), VGPR 120.
__global__ __launch_bounds__(512, 2) void simkernel(
        const _Float16* __restrict__ Ahi, const _Float16* __restrict__ Alo,
        const _Float16* __restrict__ Bhi, const _Float16* __restrict__ Blo,
        float* __restrict__ pmax, unsigned short* __restrict__ pidx) {
    __shared__ char lds_raw[5 * LBS];          // 163840 B

    int phys = blockIdx.x;
    int bid = (phys % 8) * 150 + phys / 8;     // XCD swizzle: 1200/8 = 150
    int nt = bid % 10; int t2 = bid / 10;
    int mt = t2 % 30;  int b = t2 / 30;
    int m0 = mt * 256;
    int w = nt >> 1, n0w = (nt & 1) * 256;

    int tid = threadIdx.x;
    int lane = tid & 63;
    int wvu = __builtin_amdgcn_readfirstlane(tid >> 6);

    // staging: 64 segs/K-step (A:32, B:32); each wave: 4 A segs + 4 B segs.
    int arrA = wvu >> 2;                       // 0: hi array, 1: lo array
    int rgbase = (wvu & 3) * 4;
    const char* Ab = (const char*)((arrA ? Alo : Ahi) + ((size_t)b * MPAD + m0) * CC);
    const char* Bb = (const char*)((arrA ? Blo : Bhi) + ((size_t)(b * NWAY + w) * MSP + n0w) * CC);

    int rr0 = lane >> 2;                               // row within 16-row segment
    int octsw = (lane & 3) ^ ((lane >> 3) & 3);        // XOR-swizzled octet (T2)
    int laneoff = rr0 * (CC * 2) + octsw * 16;

    const char* srcA[4]; const char* srcB[4]; int dof[4];
#pragma unroll
    for (int s = 0; s < 4; ++s) {
        int rg = rgbase + s;
        srcA[s] = Ab + (size_t)(rg * 16) * (CC * 2) + laneoff;
        srcB[s] = Bb + (size_t)(rg * 16) * (CC * 2) + laneoff;
        dof[s] = arrA * 16384 + rg * 1024;             // linear LDS dest (per slot)
    }
    char* ldsB = lds_raw + 2 * LBS;

    int wv = tid >> 6;
    int wm = wv >> 2, wn = wv & 3;                     // wave grid 2(M) x 4(N)
    int lq = lane >> 4, lc = lane & 15;

    int idxA[4], idxB[4];
#pragma unroll
    for (int mf = 0; mf < 4; ++mf) {
        int row = wm * 128 + mf * 16 + lc;
        idxA[mf] = row * 4 + (lq ^ ((row >> 1) & 3));  // +256 for mf+4 (swz invariant)
    }
#pragma unroll
    for (int nf = 0; nf < 4; ++nf) {
        int row = wn * 64 + nf * 16 + lc;
        idxB[nf] = row * 4 + (lq ^ ((row >> 1) & 3));
    }

    v4f acc[8][4];
#pragma unroll
    for (int mf = 0; mf < 8; ++mf)
#pragma unroll
        for (int nf = 0; nf < 4; ++nf) acc[mf][nf] = (v4f)0.f;

    // prologue: A(0)->Aslot0, B(0)->Bslot0, B(1)->Bslot1 (12 loads/wave in flight)
    // vmcnt(4) certifies A(0),B(0); leaves B(1)'s 4 in flight.
#pragma unroll
    for (int s = 0; s < 4; ++s) gl_lds16(srcA[s], lds_raw + dof[s]);
#pragma unroll
    for (int s = 0; s < 4; ++s) gl_lds16(srcB[s], ldsB + dof[s]);
#pragma unroll
    for (int s = 0; s < 4; ++s) gl_lds16(srcB[s] + 64, ldsB + LBS + dof[s]);
    asm volatile("s_waitcnt vmcnt(4)\n\ts_barrier" ::: "memory");

    for (int ch = 0; ch < 20; ++ch) {
        const char* cA = lds_raw + (ch & 1) * LBS;
        const char* cB = ldsB + (ch % 3) * LBS;
        const v8h* AHI = (const v8h*)cA;
        const v8h* ALO = (const v8h*)(cA + 16384);
        const v8h* BHI = (const v8h*)cB;
        const v8h* BLO = (const v8h*)(cB + 16384);
        char* nA = lds_raw + ((ch + 1) & 1) * LBS;
        char* nB = ldsB + ((ch + 2) % 3) * LBS;
        int offA = (ch + 1) * 64, offB = (ch + 2) * 64;

        v8h ahi[4], alo[4], a2hi[4], a2lo[4], bhi[4], blo[4];

        // ---- P0: reads A03(ch),B01(ch) [certified P3(ch-1)]; DMA A(ch+1)
#pragma unroll
        for (int m2 = 0; m2 < 4; ++m2) { ahi[m2] = AHI[idxA[m2]]; alo[m2] = ALO[idxA[m2]]; }
        bhi[0] = BHI[idxB[0]]; blo[0] = BLO[idxB[0]];
        bhi[1] = BHI[idxB[1]]; blo[1] = BLO[idxB[1]];
        if (ch < 19) {
#pragma unroll
            for (int s = 0; s < 4; ++s) gl_lds16(srcA[s] + offA, nA + dof[s]);
        }
        asm volatile("s_barrier\n\ts_waitcnt lgkmcnt(0)" ::: "memory");
        __builtin_amdgcn_s_setprio(1);
#pragma unroll
        for (int m2 = 0; m2 < 4; ++m2)
#pragma unroll
            for (int n2 = 0; n2 < 2; ++n2)
                acc[m2][n2] = __builtin_amdgcn_mfma_f32_16x16x32_f16(ahi[m2], bhi[n2], acc[m2][n2], 0, 0, 0);
#pragma unroll
        for (int m2 = 0; m2 < 4; ++m2)
#pragma unroll
            for (int n2 = 0; n2 < 2; ++n2)
                acc[m2][n2] = __builtin_amdgcn_mfma_f32_16x16x32_f16(ahi[m2], blo[n2], acc[m2][n2], 0, 0, 0);
#pragma unroll
        for (int m2 = 0; m2 < 4; ++m2)
#pragma unroll
            for (int n2 = 0; n2 < 2; ++n2)
                acc[m2][n2] = __builtin_amdgcn_mfma_f32_16x16x32_f16(alo[m2], bhi[n2], acc[m2][n2], 0, 0, 0);
        __builtin_amdgcn_s_setprio(0);

        // ---- P1: reads B23(ch); DMA B(ch+2) segs 0-1
        bhi[2] = BHI[idxB[2]]; blo[2] = BLO[idxB[2]];
        bhi[3] = BHI[idxB[3]]; blo[3] = BLO[idxB[3]];
        if (ch < 18) { gl_lds16(srcB[0] + offB, nB + dof[0]); gl_lds16(srcB[1] + offB, nB + dof[1]); }
        asm volatile("s_barrier\n\ts_waitcnt lgkmcnt(0)" ::: "memory");
        __builtin_amdgcn_s_setprio(1);
#pragma unroll
        for (int m2 = 0; m2 < 4; ++m2)
#pragma unroll
            for (int n2 = 2; n2 < 4; ++n2)
                acc[m2][n2] = __builtin_amdgcn_mfma_f32_16x16x32_f16(ahi[m2], bhi[n2], acc[m2][n2], 0, 0, 0);
#pragma unroll
        for (int m2 = 0; m2 < 4; ++m2)
#pragma unroll
            for (int n2 = 2; n2 < 4; ++n2)
                acc[m2][n2] = __builtin_amdgcn_mfma_f32_16x16x32_f16(ahi[m2], blo[n2], acc[m2][n2], 0, 0, 0);
#pragma unroll
        for (int m2 = 0; m2 < 4; ++m2)
#pragma unroll
            for (int n2 = 2; n2 < 4; ++n2)
                acc[m2][n2] = __builtin_amdgcn_mfma_f32_16x16x32_f16(alo[m2], bhi[n2], acc[m2][n2], 0, 0, 0);
        __builtin_amdgcn_s_setprio(0);

        // ---- P2: reads A47(ch); DMA B(ch+2) segs 2-3
#pragma unroll
        for (int m2 = 0; m2 < 4; ++m2) { a2hi[m2] = AHI[idxA[m2] + 256]; a2lo[m2] = ALO[idxA[m2] + 256]; }
        if (ch < 18) { gl_lds16(srcB[2] + offB, nB + dof[2]); gl_lds16(srcB[3] + offB, nB + dof[3]); }
        asm volatile("s_barrier\n\ts_waitcnt lgkmcnt(0)" ::: "memory");
        __builtin_amdgcn_s_setprio(1);
#pragma unroll
        for (int m2 = 0; m2 < 4; ++m2)
#pragma unroll
            for (int n2 = 0; n2 < 2; ++n2)
                acc[4 + m2][n2] = __builtin_amdgcn_mfma_f32_16x16x32_f16(a2hi[m2], bhi[n2], acc[4 + m2][n2], 0, 0, 0);
#pragma unroll
        for (int m2 = 0; m2 < 4; ++m2)
#pragma unroll
            for (int n2 = 0; n2 < 2; ++n2)
                acc[4 + m2][n2] = __builtin_amdgcn_mfma_f32_16x16x32_f16(a2hi[m2], blo[n2], acc[4 + m2][n2], 0, 0, 0);
#pragma unroll
        for (int m2 = 0; m2 < 4; ++m2)
#pragma unroll
            for (int n2 = 0; n2 < 2; ++n2)
                acc[4 + m2][n2] = __builtin_amdgcn_mfma_f32_16x16x32_f16(a2lo[m2], bhi[n2], acc[4 + m2][n2], 0, 0, 0);
        __builtin_amdgcn_s_setprio(0);

        // ---- P3: no reads; vmcnt(4) certifies A(ch+1)+B(ch+1), leaves B(ch+2)
        if (ch < 18) asm volatile("s_waitcnt vmcnt(4)\n\ts_barrier" ::: "memory");
        else         asm volatile("s_waitcnt vmcnt(0)\n\ts_barrier" ::: "memory");
        __builtin_amdgcn_s_setprio(1);
#pragma unroll
        for (int m2 = 0; m2 < 4; ++m2)
#pragma unroll
            for (int n2 = 2; n2 < 4; ++n2)
                acc[4 + m2][n2] = __builtin_amdgcn_mfma_f32_16x16x32_f16(a2hi[m2], bhi[n2], acc[4 + m2][n2], 0, 0, 0);
#pragma unroll
        for (int m2 = 0; m2 < 4; ++m2)
#pragma unroll
            for (int n2 = 2; n2 < 4; ++n2)
                acc[4 + m2][n2] = __builtin_amdgcn_mfma_f32_16x16x32_f16(a2hi[m2], blo[n2], acc[4 + m2][n2], 0, 0, 0);
#pragma unroll
        for (int m2 = 0; m2 < 4; ++m2)
#pragma unroll
            for (int n2 = 2; n2 < 4; ++n2)
                acc[4 + m2][n2] = __builtin_amdgcn_mfma_f32_16x16x32_f16(a2lo[m2], bhi[n2], acc[4 + m2][n2], 0, 0, 0);
        __builtin_amdgcn_s_setprio(0);
    }

    // ---- fused max/argmax epilogue (same tie rules as before: first-max wins) ----
    int chunk = (nt & 1) * 4 + wn;                     // 64-col chunk index of way
#pragma unroll
    for (int mf = 0; mf < 8; ++mf) {
#pragma unroll
        for (int r = 0; r < 4; ++r) {
            float v = -__builtin_inff(); int idx = 0x7fffffff;
#pragma unroll
            for (int nf = 0; nf < 4; ++nf) {
                int n_way = n0w + wn * 64 + nf * 16 + lc;
                float cv = acc[mf][nf][r];
                if (n_way < MS && cv > v) { v = cv; idx = n_way; }
            }
#pragma unroll
            for (int msk = 1; msk < 16; msk <<= 1) {
                float ov = __shfl_xor(v, msk);
                int oi = __shfl_xor(idx, msk);
                if (ov > v || (ov == v && oi < idx)) { v = ov; idx = oi; }
            }
            if (lc == 0) {
                int mrow = m0 + wm * 128 + mf * 16 + lq * 4 + r;
                size_t o = ((size_t)(b * NWAY + w) * NCH + chunk) * MPAD + mrow;
                pmax[o] = v;
                pidx[o] = (unsigned short)(idx & 0xffff);
            }
        }
    }
}

// ================= FALLBACK PATH (ws too small) =================
__global__ void norm_support(const float* __restrict__ sup, float* __restrict__ snre) {
    int bid = blockIdx.x;
    int b = bid / 25, s = bid % 25;
    int w = s / KSHOT, shot = s % KSHOT;
    const float* src = sup + (size_t)bid * CC * HW;
    float* dst = snre + ((size_t)(b * NWAY + w)) * CC * MSP + shot * HW;
    __shared__ float inv[HW];
    int t = threadIdx.x;
    if (t < HW) {
        float ss = 0.f;
        for (int c = 0; c < CC; ++c) { float v = src[c * HW + t]; ss += v * v; }
        inv[t] = 1.f / (sqrtf(ss) + EPSN);
    }
    __syncthreads();
    for (int i = t; i < CC * HW; i += 256) {
        int c = i / HW, p = i % HW;
        dst[c * MSP + p] = src[i] * inv[p];
    }
    if (shot == KSHOT - 1) {
        float* padbase = snre + ((size_t)(b * NWAY + w)) * CC * MSP;
        for (int i = t; i < CC * (MSP - MS); i += 256) {
            int c = i / (MSP - MS), j = i % (MSP - MS);
            padbase[c * MSP + MS + j] = 0.f;
        }
    }
}

__global__ __launch_bounds__(256) void simkernel_fb(
        const float* __restrict__ qx, const float* __restrict__ snre,
        float* __restrict__ pmax, unsigned short* __restrict__ pidx) {
    __shared__ char lds_fb[49152];
    v8h* AHI = (v8h*)(lds_fb);
    v8h* ALO = (v8h*)(lds_fb + 8192);
    v8h* BHI = (v8h*)(lds_fb + 16384);
    v8h* BLO = (v8h*)(lds_fb + 32768);

    int bid = blockIdx.x;
    int mt = bid % 60; int t2 = bid / 60;
    int nt = t2 % 10;  int b = t2 / 10;
    int m0 = mt * 128;
    int w = nt >> 1;
    int n0w = (nt & 1) * 256;

    int tid = threadIdx.x;
    const float* Abase = qx + (size_t)b * QQ * CC * HW;
    const float* Bbase = snre + (size_t)(b * NWAY + w) * CC * MSP;

    int oct = tid & 3;
    int arow = tid >> 2;
    int aqi[2], ap[2];
#pragma unroll
    for (int pass = 0; pass < 2; ++pass) {
        int mg = m0 + arow + pass * 64;
        if (mg >= MTOT) mg = 0;
        aqi[pass] = mg / HW; ap[pass] = mg % HW;
    }

    v4f acc[4][8];
#pragma unroll
    for (int mf = 0; mf < 4; ++mf)
#pragma unroll
        for (int nf = 0; nf < 8; ++nf) acc[mf][nf] = (v4f)0.f;

    int lane = tid & 63;
    int wv = tid >> 6;
    int mrow_w = (wv >> 1) * 64;
    int ncol_w = (wv & 1) * 128;
    int lq = lane >> 4, lc = lane & 15;

    for (int ch = 0; ch < 20; ++ch) {
        int c0 = ch * 32 + oct * 8;
        __syncthreads();
#pragma unroll
        for (int pass = 0; pass < 2; ++pass) {
            const float* src = Abase + ((size_t)aqi[pass] * CC + c0) * HW + ap[pass];
            float x[8];
#pragma unroll
            for (int j = 0; j < 8; ++j) x[j] = src[j * HW];
            v8h hi, lo; splitv(x, hi, lo);
            int cell = (arow + pass * 64) * 4 + oct;
            AHI[cell] = hi; ALO[cell] = lo;
        }
#pragma unroll
        for (int pass = 0; pass < 4; ++pass) {
            int nrow = arow + pass * 64;
            const float* src = Bbase + (size_t)c0 * MSP + n0w + nrow;
            float x[8];
#pragma unroll
            for (int j = 0; j < 8; ++j) x[j] = src[j * MSP];
            v8h hi, lo; splitv(x, hi, lo);
            int cell = nrow * 4 + oct;
            BHI[cell] = hi; BLO[cell] = lo;
        }
        __syncthreads();

        v8h ahi[4], alo[4];
#pragma unroll
        for (int mf = 0; mf < 4; ++mf) {
            int idx = (mrow_w + mf * 16 + lc) * 4 + lq;
            ahi[mf] = AHI[idx]; alo[mf] = ALO[idx];
        }
#pragma unroll
        for (int nf = 0; nf < 8; ++nf) {
            int idx = (ncol_w + nf * 16 + lc) * 4 + lq;
            v8h bhi = BHI[idx], blo = BLO[idx];
#pragma unroll
            for (int mf = 0; mf < 4; ++mf) {
                acc[mf][nf] = __builtin_amdgcn_mfma_f32_16x16x32_f16(ahi[mf], bhi, acc[mf][nf], 0, 0, 0);
                acc[mf][nf] = __builtin_amdgcn_mfma_f32_16x16x32_f16(ahi[mf], blo, acc[mf][nf], 0, 0, 0);
                acc[mf][nf] = __builtin_amdgcn_mfma_f32_16x16x32_f16(alo[mf], bhi, acc[mf][nf], 0, 0, 0);
            }
        }
    }

    int chunkidx = (nt & 1) * 2 + (wv & 1);   // 128-col chunk of the way
#pragma unroll
    for (int mf = 0; mf < 4; ++mf) {
#pragma unroll
        for (int r = 0; r < 4; ++r) {
            float v = -__builtin_inff(); int idx = 0x7fffffff;
#pragma unroll
            for (int nf = 0; nf < 8; ++nf) {
                int n_way = n0w + ncol_w + nf * 16 + lc;
                float cv = acc[mf][nf][r];
                if (n_way < MS && cv > v) { v = cv; idx = n_way; }
            }
#pragma unroll
            for (int msk = 1; msk < 16; msk <<= 1) {
                float ov = __shfl_xor(v, msk);
                int oi = __shfl_xor(idx, msk);
                if (ov > v || (ov == v && oi < idx)) { v = ov; idx = oi; }
            }
            if (lc == 0) {
                int mrow = m0 + mrow_w + mf * 16 + lq * 4 + r;
                size_t ob = (size_t)(b * NWAY + w) * NCH * MPAD + mrow;
                int s_hi = (idx != 0x7fffffff) ? (idx >> 6) : -1;  // 64-col slot
#pragma unroll
                for (int sl2 = 0; sl2 < 2; ++sl2) {
                    int sl = chunkidx * 2 + sl2;
                    if (sl == s_hi) {
                        pmax[ob + (size_t)sl * MPAD] = v;
                        pidx[ob + (size_t)sl * MPAD] = (unsigned short)(idx & 0xffff);
                    } else {
                        pmax[ob + (size_t)sl * MPAD] = -__builtin_inff();
                        pidx[ob + (size_t)sl * MPAD] = 0xffffu;
                    }
                }
            }
        }
    }
}

// ------- finalize: combine chunks + top-2 diff + mutual mask + predict + NLL -----
__global__ __launch_bounds__(128) void finalize(
        const float* __restrict__ pmax, const unsigned short* __restrict__ pidx,
        const float* __restrict__ invq, const int* __restrict__ qy,
        float* __restrict__ out) {
    int bq = blockIdx.x;
    int b = bq / QQ, qi = bq % QQ;
    __shared__ float sm[NWAY][HW];
    __shared__ int   si[NWAY][HW];
    __shared__ float diffv[HW];
    __shared__ int   nearest[HW];
    __shared__ float maskv[HW];
    __shared__ float pred[NWAY];
    int t = threadIdx.x;
    if (t < HW) {
        float iq = invq[bq * HW + t];
        for (int w = 0; w < NWAY; ++w) {
            size_t base = ((size_t)(b * NWAY + w) * NCH) * MPAD + qi * HW + t;
            float best = -__builtin_inff(); int bi = 0x7fffffff;
            for (int c = 0; c < NCH; ++c) {
                float v = pmax[base + (size_t)c * MPAD];
                if (v > best) { best = v; bi = pidx[base + (size_t)c * MPAD]; }
            }
            sm[w][t] = best * iq;
            si[w][t] = bi;
        }
    }
    __syncthreads();
    if (t < HW) {
        float v1 = -INFINITY, v2 = -INFINITY;
        float bestv = -INFINITY; int bestslot = 0;
        for (int w = 0; w < NWAY; ++w) {
            float v = sm[w][t];
            if (v > v1) { v2 = v1; v1 = v; } else if (v > v2) { v2 = v; }
            if (v > bestv) { bestv = v; bestslot = w * MS + si[w][t]; }
        }
        diffv[t] = v1 - v2;
        nearest[t] = bestslot;
    }
    __syncthreads();
    if (t < HW) {
        int slot = nearest[t];
        float bv = (nearest[0] == slot) ? diffv[0] : 0.f;
        int bm = 0;
        for (int m = 1; m < HW; ++m) {
            float val = (nearest[m] == slot) ? diffv[m] : 0.f;
            if (val > bv) { bv = val; bm = m; }
        }
        maskv[t] = (bm == t) ? TEMPER : 0.f;
    }
    __syncthreads();
    if (t < NWAY) {
        float s = 0.f;
        for (int m = 0; m < HW; ++m) s += sm[t][m] * maskv[m];
        pred[t] = s;
    }
    __syncthreads();
    if (t == 0) {
        float mx = pred[0];
        for (int w = 1; w < NWAY; ++w) mx = fmaxf(mx, pred[w]);
        float se = 0.f;
        for (int w = 0; w < NWAY; ++w) se += expf(pred[w] - mx);
        float lse = mx + logf(se);
        int y = qy[bq];
        atomicAdd(out, -(pred[y] - lse) * (1.f / (BB * QQ)));
    }
}

extern "C" void kernel_launch(void* const* d_in, const int* in_sizes, int n_in,
                              void* d_out, int out_size, void* d_ws, size_t ws_size,
                              hipStream_t stream) {
    const float* sup = (const float*)d_in[0];   // support_xf (4,25,640,10,10) f32
    const float* qx  = (const float*)d_in[2];   // query_xf   (4,75,640,10,10) f32
    const int*   qy  = (const int*)d_in[3];     // query_y    (4,75) int32
    float* out = (float*)d_out;

    // header region (~7.5 MB)
    size_t pcount = (size_t)BB * NWAY * NCH * MPAD;     // 1,228,800
    float* pmax = (float*)d_ws;
    unsigned short* pidx = (unsigned short*)(pmax + pcount);
    float* invq = (float*)(pidx + pcount);
    float* invs = invq + (size_t)BB * MTOT;             // actually BB*QQ*HW == BB*MTOT
    char*  big = (char*)(invs + (size_t)BB * 25 * HW);
    size_t header = (size_t)(big - (char*)d_ws);
    size_t needA = (size_t)BB * MPAD * CC * 2;          // 39.3 MB per array
    size_t needB = (size_t)BB * NWAY * MSP * CC * 2;    // 13.1 MB per array
    size_t need_fast = header + 2 * (needA + needB);

    hipLaunchKernelGGL(norms, dim3(BB * QQ + BB * 25), dim3(128), 0, stream,
                       qx, sup, invq, invs, out);

    if (ws_size >= need_fast) {
        _Float16* Ahi = (_Float16*)big;
        _Float16* Alo = Ahi + (size_t)BB * MPAD * CC;
        _Float16* Bhi = Alo + (size_t)BB * MPAD * CC;
        _Float16* Blo = Bhi + (size_t)BB * NWAY * MSP * CC;
        hipLaunchKernelGGL(prep_AB, dim3(BB * QQ * 10 + BB * 25 * 10), dim3(256), 0, stream,
                           qx, sup, invs, Ahi, Alo, Bhi, Blo);
        hipLaunchKernelGGL(simkernel, dim3(BB * 30 * 10), dim3(512), 0, stream,
                           Ahi, Alo, Bhi, Blo, pmax, pidx);
    } else {
        float* snre = (float*)big;   // 26.2 MB
        hipLaunchKernelGGL(norm_support, dim3(BB * 25), dim3(256), 0, stream, sup, snre);
        hipLaunchKernelGGL(simkernel_fb, dim3(BB * 10 * 60), dim3(256), 0, stream,
                           qx, snre, pmax, pidx);
    }
    hipLaunchKernelGGL(finalize, dim3(BB * QQ), dim3(128), 0, stream,
                       pmax, pidx, invq, qy, out);
}